// Round 1
// baseline (452.258 us; speedup 1.0000x reference)
//
#include <hip/hip_runtime.h>

// CNOT permutation on a batch of 2^n-amplitude state vectors (float32).
// out[b, j] = in[b, j ^ (1<<t2)]  if ((j >> c2) & 1)  else  in[b, j]
// with c2 = n - control - 1, t2 = n - target - 1.
//
// Since the batch stride is 2^n and c2,t2 < n, the bit tests/flips can be
// applied directly on the FLAT index (batch bits live above bit n-1 and are
// never touched). For c2,t2 >= 2 the permutation moves aligned groups of >=4
// consecutive floats together, so we can gather whole float4s: with i the
// float4 index, src = (i & (1<<(c2-2))) ? i ^ (1<<(t2-2)) : i.
// Both read and write streams are fully coalesced (the XOR only changes a
// high address bit; consecutive lanes stay consecutive).

__global__ __launch_bounds__(256) void
cnot_kernel(const float4* __restrict__ in, float4* __restrict__ out,
            const int* __restrict__ ctrl_p, const int* __restrict__ tgt_p,
            const int* __restrict__ nq_p, unsigned int n_vec) {
  const int n  = nq_p[0];
  const int c2 = n - ctrl_p[0] - 1;
  const int t2 = n - tgt_p[0] - 1;

  unsigned int i = blockIdx.x * blockDim.x + threadIdx.x;
  const unsigned int stride = gridDim.x * blockDim.x;

  if (c2 >= 2 && t2 >= 2) {
    // Vectorized path (taken for the benched config: c2=20, t2=13).
    const unsigned int cmask = 1u << (c2 - 2);  // control bit, in float4 units
    const unsigned int tmask = 1u << (t2 - 2);  // target flip, in float4 units
    for (; i < n_vec; i += stride) {
      const unsigned int src = (i & cmask) ? (i ^ tmask) : i;
      out[i] = in[src];
    }
  } else {
    // Scalar fallback (correctness only; not expected to run here).
    const float* inf = (const float*)in;
    float*       outf = (float*)out;
    const unsigned int cm = 1u << c2;
    const unsigned int tm = 1u << t2;
    const unsigned int n_el = n_vec * 4u;
    for (unsigned int e = i; e < n_el; e += stride) {
      const unsigned int src = (e & cm) ? (e ^ tm) : e;
      outf[e] = inf[src];
    }
  }
}

extern "C" void kernel_launch(void* const* d_in, const int* in_sizes, int n_in,
                              void* d_out, int out_size, void* d_ws, size_t ws_size,
                              hipStream_t stream) {
  const float* state = (const float*)d_in[0];
  const int* control = (const int*)d_in[1];
  const int* target  = (const int*)d_in[2];
  const int* nq      = (const int*)d_in[3];
  float* out = (float*)d_out;

  const unsigned int n_el  = (unsigned int)in_sizes[0];  // 16 * 2^24 = 2^28
  const unsigned int n_vec = n_el / 4u;                  // 2^26 float4s

  dim3 block(256);
  dim3 grid(2048);  // 256 CUs x 8 blocks; grid-stride covers the rest
  hipLaunchKernelGGL(cnot_kernel, grid, block, 0, stream,
                     (const float4*)state, (float4*)out,
                     control, target, nq, n_vec);
}